// Round 5
// baseline (212.084 us; speedup 1.0000x reference)
//
#include <hip/hip_runtime.h>
#include <math.h>

#define FDIM 512
#define TILE 16                 // samples per wave
#define WPB  4                  // waves per block
#define SPB  (TILE * WPB)       // 64 samples per block

#define RYPAIR(x, y, c, s) { float n0_ = (c)*(x) - (s)*(y); float n1_ = (s)*(x) + (c)*(y); (x) = n0_; (y) = n1_; }
#define SWAPF(x, y) { float t_ = (x); (x) = (y); (y) = t_; }

__global__ __launch_bounds__(256) void qnet_fused(
    const float4* __restrict__ in4,      // [B,512] f32, 128 float4 per row
    const float*  __restrict__ preW,     // [3,512] f32
    const float*  __restrict__ preb,     // [3] f32
    const float*  __restrict__ qp,       // [45] f32
    const float*  __restrict__ postW,    // [100,3] f32
    const float*  __restrict__ postb,    // [100] f32
    float2*       __restrict__ out,      // [B,100] f32 as [B,50] float2
    int B)
{
    __shared__ float Wlds[3 * FDIM];               // 6 KB f32 copy of pre_W
    __shared__ float pre_lds[WPB][TILE][3];

    const int tid  = threadIdx.x;
    const int lane = tid & 63;
    const int wave = tid >> 6;

    // ---- stage pre_W -> LDS, once per block (1536 floats / 256 threads) ----
    #pragma unroll
    for (int r = 0; r < 6; ++r) Wlds[tid + 256 * r] = preW[tid + 256 * r];
    __syncthreads();

    // ---- per-thread constants (L2-cached broadcast loads) ----
    const float pb0 = preb[0], pb1 = preb[1], pb2 = preb[2];

    float cw[2][3], sw[2][3];                      // shared-weight RY half-angles, qw rows 1..2
    #pragma unroll
    for (int k = 0; k < 2; ++k)
        #pragma unroll
        for (int j = 0; j < 3; ++j) {
            float th = 0.5f * qp[(k + 1) * 3 + j];
            sw[k][j] = sinf(th);
            cw[k][j] = cosf(th);
        }

    // epilogue weights: lane l (<50) produces outputs o=2l, 2l+1
    const int ol = (lane < 50) ? lane : 49;
    const float* pw = postW + 6 * ol;
    const float w00 = pw[0], w01 = pw[1], w02 = pw[2];
    const float w10 = pw[3], w11 = pw[4], w12 = pw[5];
    const float b0 = postb[2 * ol], b1 = postb[2 * ol + 1];

    // ---- Phase A: pre_out = in @ pre_W^T, 8-lane K-split, 2 passes x 8 samples ----
    const int tile_base = blockIdx.x * SPB + wave * TILE;
    const int g  = lane >> 3;                      // sample within pass (0..7)
    const int kp = lane & 7;                       // K-part (0..7): 64 features each

    #pragma unroll
    for (int p = 0; p < 2; ++p) {
        int row = tile_base + 8 * p + g;
        if (row >= B) row = B - 1;
        const float4* rp = in4 + (size_t)row * 128 + kp;
        float4 buf[16];
        #pragma unroll
        for (int i = 0; i < 16; ++i) buf[i] = rp[8 * i];  // 8 lanes x 16B contiguous per instr

        float a0a = 0.f, a0b = 0.f, a1a = 0.f, a1b = 0.f, a2a = 0.f, a2b = 0.f;
        #pragma unroll
        for (int i = 0; i < 8; ++i) {
            float4 v0 = buf[2 * i], v1 = buf[2 * i + 1];
            int fb0 = 4 * kp + 64 * i;             // feature base for v0; v1 at +32
            const float4* w0a = (const float4*)(Wlds + fb0);
            const float4* w0b = (const float4*)(Wlds + fb0 + 32);
            const float4* w1a = (const float4*)(Wlds + FDIM + fb0);
            const float4* w1b = (const float4*)(Wlds + FDIM + fb0 + 32);
            const float4* w2a = (const float4*)(Wlds + 2 * FDIM + fb0);
            const float4* w2b = (const float4*)(Wlds + 2 * FDIM + fb0 + 32);
            float4 wa;
            wa = *w0a; a0a = fmaf(v0.w, wa.w, fmaf(v0.z, wa.z, fmaf(v0.y, wa.y, fmaf(v0.x, wa.x, a0a))));
            wa = *w0b; a0b = fmaf(v1.w, wa.w, fmaf(v1.z, wa.z, fmaf(v1.y, wa.y, fmaf(v1.x, wa.x, a0b))));
            wa = *w1a; a1a = fmaf(v0.w, wa.w, fmaf(v0.z, wa.z, fmaf(v0.y, wa.y, fmaf(v0.x, wa.x, a1a))));
            wa = *w1b; a1b = fmaf(v1.w, wa.w, fmaf(v1.z, wa.z, fmaf(v1.y, wa.y, fmaf(v1.x, wa.x, a1b))));
            wa = *w2a; a2a = fmaf(v0.w, wa.w, fmaf(v0.z, wa.z, fmaf(v0.y, wa.y, fmaf(v0.x, wa.x, a2a))));
            wa = *w2b; a2b = fmaf(v1.w, wa.w, fmaf(v1.z, wa.z, fmaf(v1.y, wa.y, fmaf(v1.x, wa.x, a2b))));
        }
        float acc0 = a0a + a0b, acc1 = a1a + a1b, acc2 = a2a + a2b;
        // butterfly over the 3 K-part bits (8 lanes per sample)
        acc0 += __shfl_xor(acc0, 1); acc0 += __shfl_xor(acc0, 2); acc0 += __shfl_xor(acc0, 4);
        acc1 += __shfl_xor(acc1, 1); acc1 += __shfl_xor(acc1, 2); acc1 += __shfl_xor(acc1, 4);
        acc2 += __shfl_xor(acc2, 1); acc2 += __shfl_xor(acc2, 2); acc2 += __shfl_xor(acc2, 4);
        if (kp == 0) {
            int s = 8 * p + g;
            pre_lds[wave][s][0] = acc0;
            pre_lds[wave][s][1] = acc1;
            pre_lds[wave][s][2] = acc2;
        }
    }
    __syncthreads();

    // ---- Phase B: per-lane quantum circuit (lane owns sample lane&15, 4x redundant) ----
    const int myS = lane & 15;
    float d0 = pre_lds[wave][myS][0] + pb0;
    float d1 = pre_lds[wave][myS][1] + pb1;
    float d2 = pre_lds[wave][myS][2] + pb2;

    // q_in = tanh(d)*pi/2 ; RY half-angle = tanh(d)*pi/4
    float t0 = tanhf(d0) * 0.785398163397448f;
    float t1 = tanhf(d1) * 0.785398163397448f;
    float t2 = tanhf(d2) * 0.785398163397448f;
    float s0 = sinf(t0), c0 = cosf(t0);
    float s1 = sinf(t1), c1 = cosf(t1);
    float s2 = sinf(t2), c2 = cosf(t2);

    // product state after H-layer + per-sample RYs: amp(b0b1b2) = prod (c_j -/+ s_j) / sqrt(8)
    const float r8 = 0.353553390593274f;
    float u0m = c0 - s0, u0p = c0 + s0;
    float u1m = c1 - s1, u1p = c1 + s1;
    float u2m = (c2 - s2) * r8, u2p = (c2 + s2) * r8;
    float t00 = u0m * u1m, t01 = u0m * u1p, t10 = u0p * u1m, t11 = u0p * u1p;
    float q0 = t00 * u2m, q1 = t00 * u2p;   // idx = 4*b0 + 2*b1 + b2
    float q2 = t01 * u2m, q3 = t01 * u2p;
    float q4 = t10 * u2m, q5 = t10 * u2p;
    float q6 = t11 * u2m, q7 = t11 * u2p;

    #pragma unroll
    for (int k = 0; k < 2; ++k) {
        SWAPF(q4, q6); SWAPF(q5, q7);       // CNOT(q0 -> q1): where b0=1 flip b1
        SWAPF(q2, q3); SWAPF(q6, q7);       // CNOT(q1 -> q2): where b1=1 flip b2
        float c = cw[k][0], s = sw[k][0];   // RY on qubit 0: pairs (i, i+4)
        RYPAIR(q0, q4, c, s); RYPAIR(q1, q5, c, s); RYPAIR(q2, q6, c, s); RYPAIR(q3, q7, c, s);
        c = cw[k][1]; s = sw[k][1];         // RY on qubit 1: pairs (i, i+2)
        RYPAIR(q0, q2, c, s); RYPAIR(q1, q3, c, s); RYPAIR(q4, q6, c, s); RYPAIR(q5, q7, c, s);
        c = cw[k][2]; s = sw[k][2];         // RY on qubit 2: pairs (i, i+1)
        RYPAIR(q0, q1, c, s); RYPAIR(q2, q3, c, s); RYPAIR(q4, q5, c, s); RYPAIR(q6, q7, c, s);
    }

    float p0 = q0 * q0, p1 = q1 * q1, p2 = q2 * q2, p3 = q3 * q3;
    float p4 = q4 * q4, p5 = q5 * q5, p6 = q6 * q6, p7 = q7 * q7;
    float s01 = p0 + p1, s23 = p2 + p3, s45 = p4 + p5, s67 = p6 + p7;
    float z0 = (s01 + s23) - (s45 + s67);
    float z1 = (s01 - s23) + (s45 - s67);
    float z2 = (p0 - p1) + ((p2 - p3) + ((p4 - p5) + (p6 - p7)));

    // ---- Phase C: epilogue GEMM [*,3]x[3,100] + coalesced f32 stores ----
    #pragma unroll
    for (int s = 0; s < TILE; ++s) {
        float zz0 = __shfl(z0, s);          // lane s owns in-tile sample s
        float zz1 = __shfl(z1, s);
        float zz2 = __shfl(z2, s);
        int row = tile_base + s;
        float v0 = fmaf(zz2, w02, fmaf(zz1, w01, fmaf(zz0, w00, b0)));
        float v1 = fmaf(zz2, w12, fmaf(zz1, w11, fmaf(zz0, w10, b1)));
        if (lane < 50 && row < B) {
            float2 st; st.x = v0; st.y = v1;
            out[(size_t)row * 50 + lane] = st;   // 50 lanes x 8B = 400B/row contiguous
        }
    }
}

extern "C" void kernel_launch(void* const* d_in, const int* in_sizes, int n_in,
                              void* d_out, int out_size, void* d_ws, size_t ws_size,
                              hipStream_t stream) {
    const float4* in4   = (const float4*)d_in[0];
    const float*  preW  = (const float*)d_in[1];
    const float*  preb  = (const float*)d_in[2];
    const float*  qp    = (const float*)d_in[3];
    const float*  postW = (const float*)d_in[4];
    const float*  postb = (const float*)d_in[5];
    float2*       out   = (float2*)d_out;

    int B = in_sizes[0] / FDIM;                    // 65536
    int nblocks = (B + SPB - 1) / SPB;             // 1024
    qnet_fused<<<nblocks, 256, 0, stream>>>(in4, preW, preb, qp, postW, postb, out, B);
}

// Round 6
// 208.162 us; speedup vs baseline: 1.0188x; 1.0188x over previous
//
#include <hip/hip_runtime.h>
#include <math.h>

#define FDIM 512
#define TILE 8                  // rows per wave
#define WPB  4                  // waves per block
#define SPB  (TILE * WPB)       // 32 rows per block

#define RYPAIR(x, y, c, s) { float n0_ = (c)*(x) - (s)*(y); float n1_ = (s)*(x) + (c)*(y); (x) = n0_; (y) = n1_; }
#define SWAPF(x, y) { float t_ = (x); (x) = (y); (y) = t_; }

__global__ __launch_bounds__(256) void qnet_v2(
    const float4* __restrict__ in4,      // [B,512] f32, 128 float4 per row
    const float4* __restrict__ preW4,    // [3,512] f32 as 384 float4
    const float*  __restrict__ preb,     // [3] f32
    const float*  __restrict__ qp,       // [45] f32
    const float*  __restrict__ postW,    // [100,3] f32
    const float*  __restrict__ postb,    // [100] f32
    float2*       __restrict__ out,      // [B,100] f32 as [B,50] float2
    int B)
{
    const int tid  = threadIdx.x;
    const int lane = tid & 63;
    const int wave = tid >> 6;

    // ---- pre_W entirely in registers: lane l holds features {4l..4l+3} (a)
    //      and {256+4l..256+4l+3} (b) of each of the 3 W rows. 24 VGPRs. ----
    const float4 w0a = preW4[lane],       w0b = preW4[64 + lane];
    const float4 w1a = preW4[128 + lane], w1b = preW4[192 + lane];
    const float4 w2a = preW4[256 + lane], w2b = preW4[320 + lane];

    const float pb0 = preb[0], pb1 = preb[1], pb2 = preb[2];

    float cw[2][3], sw[2][3];              // shared-weight RY half-angles (qw rows 1..2)
    #pragma unroll
    for (int k = 0; k < 2; ++k)
        #pragma unroll
        for (int j = 0; j < 3; ++j) {
            float th = 0.5f * qp[(k + 1) * 3 + j];
            sw[k][j] = sinf(th);
            cw[k][j] = cosf(th);
        }

    // epilogue weights: lane l (<50) produces outputs o=2l, 2l+1
    const int ol = (lane < 50) ? lane : 49;
    const float* pw = postW + 6 * ol;
    const float w00 = pw[0], w01 = pw[1], w02 = pw[2];
    const float w10 = pw[3], w11 = pw[4], w12 = pw[5];
    const float b0 = postb[2 * ol], b1 = postb[2 * ol + 1];

    const int tile_base = blockIdx.x * SPB + wave * TILE;

    // ---- Phase A: wave-per-row, fully contiguous 1KB load instructions ----
    float r0 = 0.f, r1 = 0.f, r2 = 0.f;    // lane s retains row s's (d0,d1,d2)
    #pragma unroll
    for (int s = 0; s < TILE; ++s) {
        int row = tile_base + s;
        if (row >= B) row = B - 1;
        const float4* rp = in4 + (size_t)row * 128;
        float4 i0 = rp[lane];              // 64 lanes x 16B = 1KB contiguous
        float4 i1 = rp[64 + lane];         // second 1KB half of the row

        float a0 = fmaf(i0.w, w0a.w, fmaf(i0.z, w0a.z, fmaf(i0.y, w0a.y, i0.x * w0a.x)));
        a0 = fmaf(i1.w, w0b.w, fmaf(i1.z, w0b.z, fmaf(i1.y, w0b.y, fmaf(i1.x, w0b.x, a0))));
        float a1 = fmaf(i0.w, w1a.w, fmaf(i0.z, w1a.z, fmaf(i0.y, w1a.y, i0.x * w1a.x)));
        a1 = fmaf(i1.w, w1b.w, fmaf(i1.z, w1b.z, fmaf(i1.y, w1b.y, fmaf(i1.x, w1b.x, a1))));
        float a2 = fmaf(i0.w, w2a.w, fmaf(i0.z, w2a.z, fmaf(i0.y, w2a.y, i0.x * w2a.x)));
        a2 = fmaf(i1.w, w2b.w, fmaf(i1.z, w2b.z, fmaf(i1.y, w2b.y, fmaf(i1.x, w2b.x, a2))));

        // full 64-lane butterfly: every lane ends with the row sum
        #pragma unroll
        for (int m = 1; m < 64; m <<= 1) {
            a0 += __shfl_xor(a0, m);
            a1 += __shfl_xor(a1, m);
            a2 += __shfl_xor(a2, m);
        }
        bool mine = (lane == s);
        r0 = mine ? a0 : r0;
        r1 = mine ? a1 : r1;
        r2 = mine ? a2 : r2;
    }

    // ---- Phase B: per-lane quantum circuit (lane s owns row s; lanes >= TILE junk-but-finite) ----
    float d0 = r0 + pb0;
    float d1 = r1 + pb1;
    float d2 = r2 + pb2;

    // q_in = tanh(d)*pi/2 ; RY half-angle = tanh(d)*pi/4
    float t0 = tanhf(d0) * 0.785398163397448f;
    float t1 = tanhf(d1) * 0.785398163397448f;
    float t2 = tanhf(d2) * 0.785398163397448f;
    float s0 = sinf(t0), c0 = cosf(t0);
    float s1 = sinf(t1), c1 = cosf(t1);
    float s2 = sinf(t2), c2 = cosf(t2);

    // product state after H-layer + per-sample RYs: amp(b0b1b2) = prod (c_j -/+ s_j) / sqrt(8)
    const float r8 = 0.353553390593274f;
    float u0m = c0 - s0, u0p = c0 + s0;
    float u1m = c1 - s1, u1p = c1 + s1;
    float u2m = (c2 - s2) * r8, u2p = (c2 + s2) * r8;
    float t00 = u0m * u1m, t01 = u0m * u1p, t10 = u0p * u1m, t11 = u0p * u1p;
    float q0 = t00 * u2m, q1 = t00 * u2p;   // idx = 4*b0 + 2*b1 + b2
    float q2 = t01 * u2m, q3 = t01 * u2p;
    float q4 = t10 * u2m, q5 = t10 * u2p;
    float q6 = t11 * u2m, q7 = t11 * u2p;

    #pragma unroll
    for (int k = 0; k < 2; ++k) {
        SWAPF(q4, q6); SWAPF(q5, q7);       // CNOT(q0 -> q1)
        SWAPF(q2, q3); SWAPF(q6, q7);       // CNOT(q1 -> q2)
        float c = cw[k][0], s = sw[k][0];   // RY qubit 0: pairs (i, i+4)
        RYPAIR(q0, q4, c, s); RYPAIR(q1, q5, c, s); RYPAIR(q2, q6, c, s); RYPAIR(q3, q7, c, s);
        c = cw[k][1]; s = sw[k][1];         // RY qubit 1: pairs (i, i+2)
        RYPAIR(q0, q2, c, s); RYPAIR(q1, q3, c, s); RYPAIR(q4, q6, c, s); RYPAIR(q5, q7, c, s);
        c = cw[k][2]; s = sw[k][2];         // RY qubit 2: pairs (i, i+1)
        RYPAIR(q0, q1, c, s); RYPAIR(q2, q3, c, s); RYPAIR(q4, q5, c, s); RYPAIR(q6, q7, c, s);
    }

    float p0 = q0 * q0, p1 = q1 * q1, p2 = q2 * q2, p3 = q3 * q3;
    float p4 = q4 * q4, p5 = q5 * q5, p6 = q6 * q6, p7 = q7 * q7;
    float s01 = p0 + p1, s23 = p2 + p3, s45 = p4 + p5, s67 = p6 + p7;
    float z0 = (s01 + s23) - (s45 + s67);
    float z1 = (s01 - s23) + (s45 - s67);
    float z2 = (p0 - p1) + ((p2 - p3) + ((p4 - p5) + (p6 - p7)));

    // ---- Phase C: epilogue GEMM [*,3]x[3,100] + coalesced f32 stores ----
    #pragma unroll
    for (int s = 0; s < TILE; ++s) {
        float zz0 = __shfl(z0, s);          // lane s owns row s
        float zz1 = __shfl(z1, s);
        float zz2 = __shfl(z2, s);
        int row = tile_base + s;
        float v0 = fmaf(zz2, w02, fmaf(zz1, w01, fmaf(zz0, w00, b0)));
        float v1 = fmaf(zz2, w12, fmaf(zz1, w11, fmaf(zz0, w10, b1)));
        if (lane < 50 && row < B) {
            float2 st; st.x = v0; st.y = v1;
            out[(size_t)row * 50 + lane] = st;   // 50 lanes x 8B = 400B/row contiguous
        }
    }
}

extern "C" void kernel_launch(void* const* d_in, const int* in_sizes, int n_in,
                              void* d_out, int out_size, void* d_ws, size_t ws_size,
                              hipStream_t stream) {
    const float4* in4   = (const float4*)d_in[0];
    const float4* preW4 = (const float4*)d_in[1];
    const float*  preb  = (const float*)d_in[2];
    const float*  qp    = (const float*)d_in[3];
    const float*  postW = (const float*)d_in[4];
    const float*  postb = (const float*)d_in[5];
    float2*       out   = (float2*)d_out;

    int B = in_sizes[0] / FDIM;                    // 65536
    int nblocks = (B + SPB - 1) / SPB;             // 2048
    qnet_v2<<<nblocks, 256, 0, stream>>>(in4, preW4, preb, qp, postW, postb, out, B);
}